// Round 13
// baseline (336.227 us; speedup 1.0000x reference)
//
#include <hip/hip_runtime.h>
#include <hip/hip_bf16.h>
#include <math.h>

typedef __hip_bfloat16 bf16;
typedef __attribute__((ext_vector_type(8))) short short8;
typedef __attribute__((ext_vector_type(4))) float f32x4;
#define EPSF 1e-6f

__device__ __forceinline__ float b2f(bf16 v){ return __bfloat162float(v); }
__device__ __forceinline__ bf16  f2b(float v){ return __float2bfloat16(v); }
// fast softplus: abs err <3e-7 vs libm (verified absmax stable R8-R12).
__device__ __forceinline__ float spf(float x){ return x > 20.f ? x : __logf(1.f + __expf(x)); }
__device__ __forceinline__ float sigf(float x){ return 1.f/(1.f + __expf(-x)); }

__device__ __forceinline__ float wsum(float v){
#pragma unroll
  for (int m = 32; m; m >>= 1) v += __shfl_xor(v, m, 64);
  return v;
}
__device__ __forceinline__ float wmaxr(float v){
#pragma unroll
  for (int m = 32; m; m >>= 1) v = fmaxf(v, __shfl_xor(v, m, 64));
  return v;
}
__device__ __forceinline__ float wminr(float v){
#pragma unroll
  for (int m = 32; m; m >>= 1) v = fminf(v, __shfl_xor(v, m, 64));
  return v;
}

struct PrepArgs {
  const float* w0r[2]; const float* b0[2]; const float* w1r[2]; const float* b1[2];
  const float* zw[2];  const float* g0[2]; const float* g1[2]; const float* ob[2];
  bf16* W0gB[2]; bf16* MtB[2]; float* b0g[2]; float* B1g[2]; float* obm[2];
};

// Fold activations into effective weights; emit bf16 weights for MFMA hulls.
__global__ __launch_bounds__(256) void prep_kernel(PrepArgs a){
  int idx = blockIdx.x*256 + threadIdx.x;   // 0..131071
  int s = idx >> 16, r = idx & 65535;
  {
    int p = r >> 13;
    float g0 = sigf(a.g0[s][p]);
    float w  = spf(a.w0r[s][r]);
    a.W0gB[s][r] = f2b(g0 * w * w);
  }
  {
    int pd = r >> 7, kk = r & 127;
    int p = pd >> 6, d = pd & 63;
    float g1 = sigf(a.g1[s][p]);
    float w  = spf(a.w1r[s][r]);   // w1r[p,d,kk] flat == r
    float z  = a.zw[s][(p<<13) + (kk<<6) + d];
    a.MtB[s][r] = f2b(g1 * w * w + z);
  }
  if (r < 1024) a.b0g[s][r] = sigf(a.g0[s][r>>7]) * a.b0[s][r];
  if (r < 512)  a.B1g[s][r] = sigf(a.g1[s][r>>6]) * a.b1[s][r];
  if (r < 8) {
    float t = 0.f;
    for (int d = 0; d < 64; ++d) t += a.ob[s][r*64 + d];
    a.obm[s][r] = t * (1.f/64.f);
  }
}

struct HullArgs {
  const float* x[2]; const float* gw[2]; const float* gb[2]; const float* wh[2];
  const bf16* W0gB[2]; const bf16* MtB[2];
  const float* b0g[2]; const float* B1g[2]; const float* obm[2];
  float* tauOut; float* fOut[2]; float* phiOut[2];
};

// MFMA hull (R11-proven, UNCHANGED): 16 rows/block, q+k fused.
__global__ __launch_bounds__(256) void hull_kernel(HullArgs A){
  __shared__ __align__(16) bf16 xgb[16][72];
  __shared__ __align__(16) bf16 z0[16][1032];
  __shared__ float tauh[16];
  __shared__ float scoreb[16][8];
  int bid = blockIdx.x;
  int s = bid >> 10;
  int isQ = (s == 0);
  long row0 = (long)(bid & 1023) * 16;
  const float* x   = A.x[s];
  const float* gw  = A.gw[s];
  const float* wh  = A.wh[s];
  const bf16* W0gB = A.W0gB[s];
  const bf16* MtB  = A.MtB[s];
  const float* b0g = A.b0g[s];
  const float* B1g = A.B1g[s];
  const float* obm = A.obm[s];
  float* fOut   = A.fOut[s];
  float* phiOut = A.phiOut[s];
  int t = threadIdx.x, lane = t & 63, w = t >> 6;
  float gbf = A.gb[s][0];

  for (int rp = 0; rp < 4; ++rp) {
    int r = rp*4 + w;
    long row = row0 + r;
    float xv = x[row*64 + lane];
    float xh = isQ ? xv * spf(xv) : xv;
    float s1 = wsum(xh * gw[lane]);
    float g = 1.f - __expf(-spf(s1 + gbf));
    float xgv = xh * g;
    float msq = wsum(xgv*xgv)*(1.f/64.f) + EPSF;
    float th = __expf(0.30343f*sqrtf(msq) + 0.22159f);
    if (lane == 0) tauh[r] = th;
    if (isQ) {
      float m2 = wsum(xh*xh)*(1.f/64.f) + EPSF;
      if (lane == 0) A.tauOut[row] = __expf(0.30343f*sqrtf(m2) + 0.22159f);
    }
    xgb[r][lane] = f2b(xgv);
    float myphi = 0.f;
#pragma unroll
    for (int jj = 0; jj < 16; ++jj) {
      float pv = wsum(xh * wh[jj*64 + lane]);
      if (lane == jj) myphi = pv;
    }
    if (lane < 16) phiOut[row*16 + lane] = spf(fminf(myphi, 20.f)) + EPSF;
  }
  __syncthreads();

  {
    int g = lane >> 4, cl = lane & 15;
    short8 a0 = *(const short8*)&xgb[cl][g*8];
    short8 a1 = *(const short8*)&xgb[cl][32 + g*8];
    for (int ct = 0; ct < 16; ++ct) {
      int col = w*256 + ct*16 + cl;
      const short8* bp = (const short8*)(W0gB + col*64);
      short8 b0 = bp[g];
      short8 b1 = bp[4 + g];
      f32x4 acc = {0.f, 0.f, 0.f, 0.f};
      acc = __builtin_amdgcn_mfma_f32_16x16x32_bf16(a0, b0, acc, 0, 0, 0);
      acc = __builtin_amdgcn_mfma_f32_16x16x32_bf16(a1, b1, acc, 0, 0, 0);
      float bb = b0g[col];
#pragma unroll
      for (int rg = 0; rg < 4; ++rg)
        z0[g*4 + rg][col] = f2b(spf(acc[rg] + bb));
    }
  }
  __syncthreads();

  {
    int g = lane >> 4, cl = lane & 15;
    for (int pi = 0; pi < 2; ++pi) {
      int p = w + pi*4;
      short8 af[4];
#pragma unroll
      for (int kc = 0; kc < 4; ++kc)
        af[kc] = *(const short8*)&z0[cl][p*128 + kc*32 + g*8];
      float s0 = 0.f, s1 = 0.f, s2 = 0.f, s3 = 0.f;
#pragma unroll
      for (int nt = 0; nt < 4; ++nt) {
        int dcol = nt*16 + cl;
        const short8* mp = (const short8*)(MtB + (p*64 + dcol)*128);
        f32x4 acc = {0.f, 0.f, 0.f, 0.f};
#pragma unroll
        for (int kc = 0; kc < 4; ++kc)
          acc = __builtin_amdgcn_mfma_f32_16x16x32_bf16(af[kc], mp[kc*4 + g], acc, 0, 0, 0);
        float bb = B1g[p*64 + dcol];
        s0 += spf(acc[0] + bb);
        s1 += spf(acc[1] + bb);
        s2 += spf(acc[2] + bb);
        s3 += spf(acc[3] + bb);
      }
#pragma unroll
      for (int m = 1; m < 16; m <<= 1) {
        s0 += __shfl_xor(s0, m, 64);
        s1 += __shfl_xor(s1, m, 64);
        s2 += __shfl_xor(s2, m, 64);
        s3 += __shfl_xor(s3, m, 64);
      }
      if (cl == 0) {
        scoreb[g*4+0][p] = s0 * (1.f/64.f);
        scoreb[g*4+1][p] = s1 * (1.f/64.f);
        scoreb[g*4+2][p] = s2 * (1.f/64.f);
        scoreb[g*4+3][p] = s3 * (1.f/64.f);
      }
    }
  }
  __syncthreads();

  if (t < 16) {
    int r = t;
    float th = tauh[r];
    float li[8]; float m = -1e30f;
#pragma unroll
    for (int p = 0; p < 8; ++p) { li[p] = (scoreb[r][p] + obm[p]) * th; m = fmaxf(m, li[p]); }
    float ssum = 0.f;
#pragma unroll
    for (int p = 0; p < 8; ++p) ssum += __expf(li[p] - m);
    fOut[row0 + r] = (m + __logf(ssum)) / th;
  }
}

// Fused attention. R13: R12 structure + latency-hiding — PV runs two independent
// j-streams (j, j+256) with separate accumulators and unroll 8 (up to 16
// outstanding v loads); phase A unroll 4. Math = same sums regrouped.
__global__ __launch_bounds__(512) void attn2_kernel(
  const float* __restrict__ mask, const float* __restrict__ vv,
  const float* __restrict__ phiQ, const float* __restrict__ phiK,
  const float* __restrict__ fqA, const float* __restrict__ gkA, const float* __restrict__ tauA,
  float* __restrict__ eBuf, float* __restrict__ outO)
{
  __shared__ __align__(16) float lg[8][1024];
  __shared__ __align__(16) float wsm[2][1024];
  __shared__ __align__(16) float pvp[2][8][2][64];  // [buf][lrow][j-half][d], sinv applied
  __shared__ float phq[16][16];
  __shared__ float fqs[16], taus[16], sinvL[8];
  __shared__ float red8[8], red8b[8];
  int t = threadIdx.x, lane = t & 63, w = t >> 6;
  int b = blockIdx.x >> 9, it = blockIdx.x & 511;
  int i0 = it * 2;

  if (t < 256) { int row = t>>4, jj = t&15;
    phq[row][jj] = phiQ[((long)(b*8 + (row>>1))*1024 + i0 + (row&1))*16 + jj]; }
  else if (t < 272) { int row = t-256;
    fqs[row] = fqA[(long)(b*8 + (row>>1))*1024 + i0 + (row&1)]; }
  else if (t < 288) { int row = t-272;
    taus[row] = tauA[(long)(b*8 + (row>>1))*1024 + i0 + (row&1)]; }
  __syncthreads();

  int hl = w & 3, rr = w >> 2;     // wave -> (head-in-group, j-half / phaseA-row)
  int lrow = hl*2 + rr;

  for (int g = 0; g < 2; ++g) {
    int h = g*4 + hl;
    int bh = b*8 + h;
    int grow = g*8 + lrow;

    // ---- deferred combine of previous group's PV partials (after its barrier) ----
    if (g > 0) {
      int r = t >> 6, d = t & 63;
      int hh = (g-1)*4 + (r >> 1), rrow = r & 1;
      outO[((long)(b*8 + hh)*1024 + i0 + rrow)*64 + d] =
        pvp[(g-1)&1][r][0][d] + pvp[(g-1)&1][r][1][d];
    }

    // ---- phase A: logits for own row (all 8 waves) ----
    {
      float pq[16];
#pragma unroll
      for (int c = 0; c < 16; ++c) pq[c] = phq[grow][c];
      float fq = fqs[grow], ta = taus[grow];
      const float* pkb = phiK + (long)bh*16384;
      const float* mrow = mask + ((long)bh*1024 + i0 + rr)*1024;
      const float* gkb = gkA + (long)bh*1024;
#pragma unroll 4
      for (int jj = 0; jj < 16; ++jj) {
        int j = jj*64 + lane;
        const float4* pk = (const float4*)(pkb + j*16);
        float4 k0 = pk[0], k1 = pk[1], k2 = pk[2], k3 = pk[3];
        float dp = pq[0]*k0.x + pq[1]*k0.y + pq[2]*k0.z + pq[3]*k0.w
                 + pq[4]*k1.x + pq[5]*k1.y + pq[6]*k1.z + pq[7]*k1.w
                 + pq[8]*k2.x + pq[9]*k2.y + pq[10]*k2.z + pq[11]*k2.w
                 + pq[12]*k3.x + pq[13]*k3.y + pq[14]*k3.z + pq[15]*k3.w;
        float mk = fmaxf(mrow[j], EPSF);
        float sc = fq + gkb[j] + __logf(dp * mk);
        lg[lrow][j] = sc * ta;
      }
    }
    // ---- per-row softmax (wave owns lrow; wave-internal) ----
    {
      float m = -1e30f;
#pragma unroll
      for (int c = 0; c < 16; ++c) m = fmaxf(m, lg[lrow][c*64 + lane]);
      m = wmaxr(m);
      float s = 0.f;
#pragma unroll
      for (int c = 0; c < 16; ++c) {
        float e = __expf(lg[lrow][c*64 + lane] - m);
        lg[lrow][c*64 + lane] = e;
        s += e;
      }
      s = wsum(s);
      if (lane == 0) sinvL[lrow] = 1.f / s;
    }
    __syncthreads();   // all e-values + sinvL visible

    // ---- Sum_h w accumulation (all 512 threads, 4 floats each) ----
    {
      int r = t >> 8, j4 = (t & 255) * 4;
      float4 acc;
      if (g == 0) acc = make_float4(0.f,0.f,0.f,0.f);
      else        acc = *(float4*)&wsm[r][j4];
#pragma unroll
      for (int q = 0; q < 4; ++q) {
        float sv = sinvL[q*2 + r];
        float4 e = *(const float4*)&lg[q*2 + r][j4];
        acc.x += sv*e.x; acc.y += sv*e.y; acc.z += sv*e.z; acc.w += sv*e.w;
      }
      *(float4*)&wsm[r][j4] = acc;
    }
    // ---- PV partials (ALL 8 waves): head hl, j-half rr, BOTH rows ----
    // Two independent j-streams (jA, jA+256) for deep load pipelining.
    {
      int d4 = lane & 15, jg = lane >> 4;
      int r0 = hl*2, r1 = r0 + 1;
      float si0 = sinvL[r0], si1 = sinvL[r1];
      const float* vb = vv + (long)bh*65536 + d4*4;
      float4 a0 = make_float4(0.f,0.f,0.f,0.f);
      float4 a1 = make_float4(0.f,0.f,0.f,0.f);
      float4 c0 = make_float4(0.f,0.f,0.f,0.f);
      float4 c1 = make_float4(0.f,0.f,0.f,0.f);
      int jbase = rr*512 + jg;
#pragma unroll 8
      for (int jt = 0; jt < 64; ++jt) {
        int jA = jbase + jt*4;
        int jB = jA + 256;
        float4 vfA = *(const float4*)(vb + (long)jA*64);
        float4 vfB = *(const float4*)(vb + (long)jB*64);
        float pA0 = lg[r0][jA], pA1 = lg[r1][jA];
        float pB0 = lg[r0][jB], pB1 = lg[r1][jB];
        a0.x += pA0*vfA.x; a0.y += pA0*vfA.y; a0.z += pA0*vfA.z; a0.w += pA0*vfA.w;
        a1.x += pA1*vfA.x; a1.y += pA1*vfA.y; a1.z += pA1*vfA.z; a1.w += pA1*vfA.w;
        c0.x += pB0*vfB.x; c0.y += pB0*vfB.y; c0.z += pB0*vfB.z; c0.w += pB0*vfB.w;
        c1.x += pB1*vfB.x; c1.y += pB1*vfB.y; c1.z += pB1*vfB.z; c1.w += pB1*vfB.w;
      }
      a0.x += c0.x; a0.y += c0.y; a0.z += c0.z; a0.w += c0.w;
      a1.x += c1.x; a1.y += c1.y; a1.z += c1.z; a1.w += c1.w;
      // reduce over jg (lane bits 4,5)
      a0.x += __shfl_xor(a0.x,16,64); a0.y += __shfl_xor(a0.y,16,64);
      a0.z += __shfl_xor(a0.z,16,64); a0.w += __shfl_xor(a0.w,16,64);
      a0.x += __shfl_xor(a0.x,32,64); a0.y += __shfl_xor(a0.y,32,64);
      a0.z += __shfl_xor(a0.z,32,64); a0.w += __shfl_xor(a0.w,32,64);
      a1.x += __shfl_xor(a1.x,16,64); a1.y += __shfl_xor(a1.y,16,64);
      a1.z += __shfl_xor(a1.z,16,64); a1.w += __shfl_xor(a1.w,16,64);
      a1.x += __shfl_xor(a1.x,32,64); a1.y += __shfl_xor(a1.y,32,64);
      a1.z += __shfl_xor(a1.z,32,64); a1.w += __shfl_xor(a1.w,32,64);
      if (jg == 0) {
        float4 o0 = make_float4(a0.x*si0, a0.y*si0, a0.z*si0, a0.w*si0);
        float4 o1 = make_float4(a1.x*si1, a1.y*si1, a1.z*si1, a1.w*si1);
        *(float4*)&pvp[g&1][r0][rr][d4*4] = o0;
        *(float4*)&pvp[g&1][r1][rr][d4*4] = o1;
      }
    }
    __syncthreads();   // protect lg/wsm/sinvL + publish pvp
  }

  // ---- final combine for group 1 ----
  {
    int r = t >> 6, d = t & 63;
    int hh = 4 + (r >> 1), rrow = r & 1;
    outO[((long)(b*8 + hh)*1024 + i0 + rrow)*64 + d] =
      pvp[1][r][0][d] + pvp[1][r][1][d];
  }

  // ---- row-softmax of Sum_h w -> a-contribution rows (all 512 threads) ----
  {
    int r = t >> 8, j4 = (t & 255) * 4;
    float4 wv = *(const float4*)&wsm[r][j4];
    float m2 = fmaxf(fmaxf(wv.x, wv.y), fmaxf(wv.z, wv.w));
    m2 = wmaxr(m2);
    if (lane == 0) red8[w] = m2;
    __syncthreads();
    int base = r*4;
    m2 = fmaxf(fmaxf(red8[base], red8[base+1]), fmaxf(red8[base+2], red8[base+3]));
    float4 e4;
    e4.x = __expf(wv.x - m2); e4.y = __expf(wv.y - m2);
    e4.z = __expf(wv.z - m2); e4.w = __expf(wv.w - m2);
    float ls = e4.x + e4.y + e4.z + e4.w;
    ls = wsum(ls);
    if (lane == 0) red8b[w] = ls;
    __syncthreads();
    float s2 = red8b[base] + red8b[base+1] + red8b[base+2] + red8b[base+3];
    float sc = 1.f / (s2 * 1024.f);
    float4 o = make_float4(e4.x*sc, e4.y*sc, e4.z*sc, e4.w*sc);
    *(float4*)&eBuf[((long)b*1024 + i0 + r)*1024 + j4] = o;
  }
}

// a[b,j] = Sum_i eBuf[b,i,j]; 32 i-rows per block, low-contention atomics.
__global__ __launch_bounds__(256) void reduce_kernel(const float* __restrict__ eBuf, float* __restrict__ aAcc){
  int b = blockIdx.x >> 5, ii = blockIdx.x & 31;
  int t = threadIdx.x;
  const float* base = eBuf + ((long)b*1024 + ii*32)*1024 + t*4;
  float4 acc = make_float4(0.f,0.f,0.f,0.f);
  for (int i = 0; i < 32; ++i) {
    float4 v = *(const float4*)(base + (long)i*1024);
    acc.x += v.x; acc.y += v.y; acc.z += v.z; acc.w += v.w;
  }
  atomicAdd(&aAcc[b*1024 + t*4+0], acc.x);
  atomicAdd(&aAcc[b*1024 + t*4+1], acc.y);
  atomicAdd(&aAcc[b*1024 + t*4+2], acc.z);
  atomicAdd(&aAcc[b*1024 + t*4+3], acc.w);
}

// min-max normalize a, write fp32
__global__ __launch_bounds__(1024) void anorm_kernel(const float* __restrict__ aAcc, float* __restrict__ outA){
  int b = blockIdx.x, t = threadIdx.x, lane = t & 63, w = t >> 6;
  float v = aAcc[b*1024 + t];
  __shared__ float rmn[16], rmx[16];
  float mn = wminr(v), mx = wmaxr(v);
  if (lane == 0) { rmn[w] = mn; rmx[w] = mx; }
  __syncthreads();
  mn = rmn[0]; mx = rmx[0];
#pragma unroll
  for (int i = 1; i < 16; ++i) { mn = fminf(mn, rmn[i]); mx = fmaxf(mx, rmx[i]); }
  outA[b*1024 + t] = (v - mn) / (mx - mn + EPSF);
}

extern "C" void kernel_launch(void* const* d_in, const int* in_sizes, int n_in,
                              void* d_out, int out_size, void* d_ws, size_t ws_size,
                              hipStream_t stream)
{
  (void)in_sizes; (void)n_in; (void)out_size; (void)ws_size;
  const float* q    = (const float*)d_in[0];
  const float* k    = (const float*)d_in[1];
  const float* v    = (const float*)d_in[2];
  const float* mask = (const float*)d_in[3];
  const float* whq  = (const float*)d_in[4];
  const float* whk  = (const float*)d_in[5];

  float* ws = (float*)d_ws;          // ~10.7 MB
  bf16* w0b_q = (bf16*)(ws);
  bf16* w0b_k = (bf16*)(ws + 32768);
  bf16* mtb_q = (bf16*)(ws + 65536);
  bf16* mtb_k = (bf16*)(ws + 98304);
  float* b0g_q = ws + 131072;
  float* b0g_k = ws + 132096;
  float* B1g_q = ws + 133120;
  float* B1g_k = ws + 133632;
  float* obm_q = ws + 134144;
  float* obm_k = ws + 134160;
  float* tau_q = ws + 134176;
  float* fq_a  = ws + 150560;
  float* gk_a  = ws + 166944;
  float* phi_q = ws + 183328;
  float* phi_k = ws + 445472;
  float* e_buf = ws + 707616;
  float* a_acc = ws + 2804768;

  hipMemsetAsync(a_acc, 0, 2048*sizeof(float), stream);

  PrepArgs pa;
  for (int s = 0; s < 2; ++s) {
    int o = 6 + 10*s;
    pa.w0r[s] = (const float*)d_in[o+0];
    pa.b0 [s] = (const float*)d_in[o+1];
    pa.w1r[s] = (const float*)d_in[o+2];
    pa.b1 [s] = (const float*)d_in[o+3];
    pa.zw [s] = (const float*)d_in[o+4];
    pa.g0 [s] = (const float*)d_in[o+5];
    pa.g1 [s] = (const float*)d_in[o+6];
    pa.ob [s] = (const float*)d_in[o+7];
  }
  pa.W0gB[0]=w0b_q; pa.W0gB[1]=w0b_k; pa.MtB[0]=mtb_q; pa.MtB[1]=mtb_k;
  pa.b0g[0]=b0g_q; pa.b0g[1]=b0g_k; pa.B1g[0]=B1g_q; pa.B1g[1]=B1g_k;
  pa.obm[0]=obm_q; pa.obm[1]=obm_k;

  prep_kernel<<<512,256,0,stream>>>(pa);

  HullArgs ha;
  ha.x[0] = q; ha.x[1] = k;
  ha.gw[0] = (const float*)d_in[14]; ha.gw[1] = (const float*)d_in[24];
  ha.gb[0] = (const float*)d_in[15]; ha.gb[1] = (const float*)d_in[25];
  ha.wh[0] = whq; ha.wh[1] = whk;
  ha.W0gB[0] = w0b_q; ha.W0gB[1] = w0b_k;
  ha.MtB[0] = mtb_q;  ha.MtB[1] = mtb_k;
  ha.b0g[0] = b0g_q;  ha.b0g[1] = b0g_k;
  ha.B1g[0] = B1g_q;  ha.B1g[1] = B1g_k;
  ha.obm[0] = obm_q;  ha.obm[1] = obm_k;
  ha.tauOut = tau_q;
  ha.fOut[0] = fq_a;  ha.fOut[1] = gk_a;
  ha.phiOut[0] = phi_q; ha.phiOut[1] = phi_k;

  hull_kernel<<<2048,256,0,stream>>>(ha);

  attn2_kernel<<<1024,512,0,stream>>>(mask, v, phi_q, phi_k, fq_a, gk_a, tau_q,
                                      e_buf, (float*)d_out);
  reduce_kernel<<<64,256,0,stream>>>(e_buf, a_acc);
  anorm_kernel<<<2,1024,0,stream>>>(a_acc, (float*)d_out + 1048576);
}